// Round 1
// baseline (751.384 us; speedup 1.0000x reference)
//
#include <hip/hip_runtime.h>
#include <hip/hip_bf16.h>
#include <math.h>

// Problem constants (fixed by reference)
constexpr int BB = 4;
constexpr int LL = 2048;
constexpr int EE = 512;
constexpr int HH = 8;
constexpr int DD = 64;
constexpr int UU = 40;    // sample count
constexpr int NT = 40;    // n_top
constexpr float NEG_INF = -3.0e38f;

// ---------------------------------------------------------------------------
// K1: fused QKV projection GEMM (NT layout: out[m,n] = sum_k X[m,k]*W[n,k] + b[n])
// M=8192, N=512, K=512. BM=BN=128, BK=16, 256 threads, 8x8 microtile.
// Output written directly in (B,H,L,D) layout.
// ---------------------------------------------------------------------------
constexpr int PBM = 128, PBN = 128, PBK = 16;

__global__ __launch_bounds__(256) void proj_kernel(
    const float* __restrict__ Xq, const float* __restrict__ Xk, const float* __restrict__ Xv,
    const float* __restrict__ Wq, const float* __restrict__ Wk, const float* __restrict__ Wv,
    const float* __restrict__ bq, const float* __restrict__ bk, const float* __restrict__ bv,
    float* __restrict__ Oq, float* __restrict__ Ok, float* __restrict__ Ov)
{
    const float* X; const float* W; const float* bias; float* O;
    if (blockIdx.z == 0)      { X = Xq; W = Wq; bias = bq; O = Oq; }
    else if (blockIdx.z == 1) { X = Xk; W = Wk; bias = bk; O = Ok; }
    else                      { X = Xv; W = Wv; bias = bv; O = Ov; }

    __shared__ float As[PBK][PBM];
    __shared__ float Bs[PBK][PBN];

    const int tid  = threadIdx.x;
    const int lane = tid & 63;
    const int wv   = tid >> 6;
    // wave-quadrant map: within a wave tx spans 8 values (2-way LDS alias, free),
    // ty spans 8 values (broadcast).
    const int tx = ((wv & 1) << 3) + (lane & 7);   // 0..15
    const int ty = ((wv >> 1) << 3) + (lane >> 3); // 0..15

    const int m0 = blockIdx.y * PBM;
    const int n0 = blockIdx.x * PBN;

    const int lrow = tid >> 1;        // 0..127
    const int lcol = (tid & 1) * 8;   // 0 or 8

    float acc[8][8];
#pragma unroll
    for (int i = 0; i < 8; i++)
#pragma unroll
        for (int j = 0; j < 8; j++) acc[i][j] = 0.0f;

    const float* Arow = X + (size_t)(m0 + lrow) * EE + lcol;
    const float* Brow = W + (size_t)(n0 + lrow) * EE + lcol;

    for (int kt = 0; kt < EE; kt += PBK) {
        float4 a0 = *(const float4*)(Arow + kt);
        float4 a1 = *(const float4*)(Arow + kt + 4);
        float4 b0 = *(const float4*)(Brow + kt);
        float4 b1 = *(const float4*)(Brow + kt + 4);
        __syncthreads();
        As[lcol + 0][lrow] = a0.x; As[lcol + 1][lrow] = a0.y;
        As[lcol + 2][lrow] = a0.z; As[lcol + 3][lrow] = a0.w;
        As[lcol + 4][lrow] = a1.x; As[lcol + 5][lrow] = a1.y;
        As[lcol + 6][lrow] = a1.z; As[lcol + 7][lrow] = a1.w;
        Bs[lcol + 0][lrow] = b0.x; Bs[lcol + 1][lrow] = b0.y;
        Bs[lcol + 2][lrow] = b0.z; Bs[lcol + 3][lrow] = b0.w;
        Bs[lcol + 4][lrow] = b1.x; Bs[lcol + 5][lrow] = b1.y;
        Bs[lcol + 6][lrow] = b1.z; Bs[lcol + 7][lrow] = b1.w;
        __syncthreads();
#pragma unroll
        for (int k = 0; k < PBK; k++) {
            float4 av0 = *(const float4*)&As[k][ty * 8];
            float4 av1 = *(const float4*)&As[k][ty * 8 + 4];
            float4 bv0 = *(const float4*)&Bs[k][tx * 8];
            float4 bv1 = *(const float4*)&Bs[k][tx * 8 + 4];
            float a[8] = {av0.x, av0.y, av0.z, av0.w, av1.x, av1.y, av1.z, av1.w};
            float b[8] = {bv0.x, bv0.y, bv0.z, bv0.w, bv1.x, bv1.y, bv1.z, bv1.w};
#pragma unroll
            for (int i = 0; i < 8; i++)
#pragma unroll
                for (int j = 0; j < 8; j++) acc[i][j] += a[i] * b[j];
        }
    }

    // epilogue: add bias, write to (B,H,L,D)
    const int hh = (n0 >> 6) + ((tx * 8) >> 6);
    const int dd = (tx * 8) & 63;
    float bias8[8];
#pragma unroll
    for (int j = 0; j < 8; j++) bias8[j] = bias[n0 + tx * 8 + j];

#pragma unroll
    for (int r = 0; r < 8; r++) {
        int m  = m0 + ty * 8 + r;
        int b_ = m >> 11;
        int l_ = m & (LL - 1);
        float* orow = O + (((size_t)(b_ * HH + hh) * LL + l_) << 6) + dd;
        float4 o0 = {acc[r][0] + bias8[0], acc[r][1] + bias8[1],
                     acc[r][2] + bias8[2], acc[r][3] + bias8[3]};
        float4 o1 = {acc[r][4] + bias8[4], acc[r][5] + bias8[5],
                     acc[r][6] + bias8[6], acc[r][7] + bias8[7]};
        *(float4*)(orow)     = o0;
        *(float4*)(orow + 4) = o1;
    }
}

// ---------------------------------------------------------------------------
// K2: mean of V over L per (b,h)
// ---------------------------------------------------------------------------
__global__ __launch_bounds__(256) void meanv_kernel(const float* __restrict__ v,
                                                    float* __restrict__ mean_v)
{
    int bh = blockIdx.x;
    int d  = threadIdx.x & 63;
    int g  = threadIdx.x >> 6;
    const float* base = v + (size_t)bh * LL * DD;
    float acc = 0.0f;
    for (int l = g; l < LL; l += 4) acc += base[(size_t)l * DD + d];
    __shared__ float red[4][DD];
    red[g][d] = acc;
    __syncthreads();
    if (g == 0) {
        float s = red[0][d] + red[1][d] + red[2][d] + red[3][d];
        mean_v[bh * DD + d] = s * (1.0f / (float)LL);
    }
}

// ---------------------------------------------------------------------------
// K3: sparsity measure M[b,h,l] = max_s(q.k_sample) - sum_s(q.k_sample)/L
// One wave per (b,h,l).
// ---------------------------------------------------------------------------
__global__ __launch_bounds__(256) void measure_kernel(const float* __restrict__ q,
                                                      const float* __restrict__ k,
                                                      const int* __restrict__ idx_sample,
                                                      float* __restrict__ M)
{
    int bh   = blockIdx.x;
    int lane = threadIdx.x & 63;
    int wv   = threadIdx.x >> 6;
    int l    = blockIdx.y * 4 + wv;

    const float* qrow  = q + ((size_t)bh * LL + l) * DD;
    const float* kbase = k + (size_t)bh * LL * DD;
    float qv = qrow[lane];

    float mx = NEG_INF, sum = 0.0f;
    for (int s = 0; s < UU; s++) {
        int ki   = idx_sample[l * UU + s];
        float p  = qv * kbase[(size_t)ki * DD + lane];
#pragma unroll
        for (int off = 32; off > 0; off >>= 1) p += __shfl_down(p, off, 64);
        if (lane == 0) { mx = fmaxf(mx, p); sum += p; }
    }
    if (lane == 0) M[bh * LL + l] = mx - sum * (1.0f / (float)LL);
}

// ---------------------------------------------------------------------------
// K4: top-40 indices of M per (b,h) (iterative masked max, ties -> lowest idx)
// ---------------------------------------------------------------------------
__global__ __launch_bounds__(256) void topk_kernel(const float* __restrict__ M,
                                                   int* __restrict__ top)
{
    int bh  = blockIdx.x;
    int tid = threadIdx.x;
    __shared__ float vals[LL];
    __shared__ float rv[256];
    __shared__ int   ri[256];

    for (int i = tid; i < LL; i += 256) vals[i] = M[bh * LL + i];
    __syncthreads();

    for (int it = 0; it < NT; it++) {
        float bv = NEG_INF;
        int   bi = 0x7fffffff;
        for (int i = tid; i < LL; i += 256) {
            float vvv = vals[i];
            if (vvv > bv || (vvv == bv && i < bi)) { bv = vvv; bi = i; }
        }
        rv[tid] = bv; ri[tid] = bi;
        __syncthreads();
        for (int s = 128; s > 0; s >>= 1) {
            if (tid < s) {
                float ov = rv[tid + s]; int oi = ri[tid + s];
                if (ov > rv[tid] || (ov == rv[tid] && oi < ri[tid])) {
                    rv[tid] = ov; ri[tid] = oi;
                }
            }
            __syncthreads();
        }
        if (tid == 0) { top[bh * NT + it] = ri[0]; vals[ri[0]] = NEG_INF; }
        __syncthreads();
    }
}

// ---------------------------------------------------------------------------
// K5: full attention for the 40 selected rows per (b,h):
//     scores = q_sel . k (2048), softmax, upd = attn @ v
// One block per (b,h,u).
// ---------------------------------------------------------------------------
__global__ __launch_bounds__(256) void attn_kernel(const float* __restrict__ q,
                                                   const float* __restrict__ k,
                                                   const float* __restrict__ v,
                                                   const int* __restrict__ top,
                                                   float* __restrict__ upd)
{
    int bhu = blockIdx.x;
    int bh  = bhu / NT;
    int tid = threadIdx.x;

    __shared__ float qs[DD];
    __shared__ float sc[LL];
    __shared__ float red[256];
    __shared__ float pv[4][DD];

    int l = top[bhu];
    if (tid < DD) qs[tid] = q[((size_t)bh * LL + l) * DD + tid];
    __syncthreads();

    const float* kbase = k + (size_t)bh * LL * DD;
    float myscore[8];
    float lmax = NEG_INF;
#pragma unroll
    for (int j = 0; j < 8; j++) {
        int kk = tid + j * 256;
        const float* krow = kbase + (size_t)kk * DD;
        float acc = 0.0f;
#pragma unroll
        for (int d4 = 0; d4 < 16; d4++) {
            float4 kv = *(const float4*)(krow + d4 * 4);
            float4 qv = *(const float4*)(qs + d4 * 4);
            acc += kv.x * qv.x + kv.y * qv.y + kv.z * qv.z + kv.w * qv.w;
        }
        myscore[j] = acc;
        lmax = fmaxf(lmax, acc);
    }
    red[tid] = lmax;
    __syncthreads();
    for (int s = 128; s > 0; s >>= 1) {
        if (tid < s) red[tid] = fmaxf(red[tid], red[tid + s]);
        __syncthreads();
    }
    float gmax = red[0];
    __syncthreads();

    float lsum = 0.0f;
#pragma unroll
    for (int j = 0; j < 8; j++) {
        float e = __expf(myscore[j] - gmax);
        sc[tid + j * 256] = e;
        lsum += e;
    }
    red[tid] = lsum;
    __syncthreads();
    for (int s = 128; s > 0; s >>= 1) {
        if (tid < s) red[tid] += red[tid + s];
        __syncthreads();
    }
    float inv = 1.0f / red[0];

    // PV: wave w handles keys [w*512, w*512+512); lane = d
    int lane = tid & 63, wv = tid >> 6;
    const float* vbase = v + (size_t)bh * LL * DD;
    float acc = 0.0f;
    for (int kk = wv * 512; kk < wv * 512 + 512; kk++) {
        acc += sc[kk] * vbase[(size_t)kk * DD + lane];
    }
    pv[wv][lane] = acc;
    __syncthreads();
    if (tid < DD) {
        float s = pv[0][tid] + pv[1][tid] + pv[2][tid] + pv[3][tid];
        upd[(size_t)bhu * DD + tid] = s * inv;
    }
}

// ---------------------------------------------------------------------------
// K6a: base output row per batch: base[b,e] = meanctx[b,:] . Wo[e,:] + bo[e]
// One wave per (b,e).
// ---------------------------------------------------------------------------
__global__ __launch_bounds__(256) void base_kernel(const float* __restrict__ mean_v,
                                                   const float* __restrict__ Wo,
                                                   const float* __restrict__ bo,
                                                   float* __restrict__ base)
{
    int lane = threadIdx.x & 63, wv = threadIdx.x >> 6;
    int be = blockIdx.x * 4 + wv;
    int b  = be >> 9;
    int e  = be & (EE - 1);
    const float* mrow = mean_v + b * EE;   // (b,h,d) contiguous = concat over heads
    const float* wrow = Wo + (size_t)e * EE;
    float acc = 0.0f;
#pragma unroll
    for (int j = 0; j < 8; j++) acc += mrow[lane + j * 64] * wrow[lane + j * 64];
#pragma unroll
    for (int off = 32; off > 0; off >>= 1) acc += __shfl_down(acc, off, 64);
    if (lane == 0) base[be] = acc + bo[e];
}

// ---------------------------------------------------------------------------
// K6b: broadcast base row to all l: out[b,l,:] = base[b,:]
// ---------------------------------------------------------------------------
__global__ __launch_bounds__(256) void bcast_kernel(const float* __restrict__ base,
                                                    float* __restrict__ out)
{
    size_t fi = ((size_t)blockIdx.x * 256 + threadIdx.x) * 4;
    int b  = (int)(fi >> 20);          // / (2048*512)
    int e4 = (int)(fi & (EE - 1));
    float4 val = *(const float4*)(base + b * EE + e4);
    *(float4*)(out + fi) = val;
}

// ---------------------------------------------------------------------------
// K6c: corrections: out[b,l_sel,:] += (upd - mean_v) . Wo_h^T   (atomic)
// One block per (b,h,u).
// ---------------------------------------------------------------------------
__global__ __launch_bounds__(256) void corr_kernel(const float* __restrict__ upd,
                                                   const float* __restrict__ mean_v,
                                                   const int* __restrict__ top,
                                                   const float* __restrict__ Wo,
                                                   float* __restrict__ out)
{
    int bhu = blockIdx.x;
    int bh  = bhu / NT;
    int h   = bh & (HH - 1);
    int b   = bh >> 3;
    int tid = threadIdx.x;
    int l   = top[bhu];

    __shared__ float delta[DD];
    if (tid < DD) delta[tid] = upd[(size_t)bhu * DD + tid] - mean_v[bh * DD + tid];
    __syncthreads();

    float* orow = out + ((size_t)(b * LL + l)) * EE;
#pragma unroll
    for (int rep = 0; rep < 2; rep++) {
        int e = tid + rep * 256;
        const float* wrow = Wo + (size_t)e * EE + h * DD;
        float acc = 0.0f;
#pragma unroll
        for (int d = 0; d < DD; d++) acc += delta[d] * wrow[d];
        atomicAdd(orow + e, acc);
    }
}

// ---------------------------------------------------------------------------
extern "C" void kernel_launch(void* const* d_in, const int* in_sizes, int n_in,
                              void* d_out, int out_size, void* d_ws, size_t ws_size,
                              hipStream_t stream)
{
    const float* query = (const float*)d_in[0];
    const float* key   = (const float*)d_in[1];
    const float* value = (const float*)d_in[2];
    const int*   idxs  = (const int*)d_in[3];
    const float* Wq = (const float*)d_in[4];
    const float* bq = (const float*)d_in[5];
    const float* Wk = (const float*)d_in[6];
    const float* bk = (const float*)d_in[7];
    const float* Wv = (const float*)d_in[8];
    const float* bv = (const float*)d_in[9];
    const float* Wo = (const float*)d_in[10];
    const float* bo = (const float*)d_in[11];
    float* out = (float*)d_out;

    // workspace layout
    char* ws = (char*)d_ws;
    size_t off = 0;
    const size_t qkv_bytes = (size_t)BB * HH * LL * DD * sizeof(float); // 16 MB each
    float* q_ws = (float*)(ws + off); off += qkv_bytes;
    float* k_ws = (float*)(ws + off); off += qkv_bytes;
    float* v_ws = (float*)(ws + off); off += qkv_bytes;
    float* M_ws    = (float*)(ws + off); off += (size_t)BB * HH * LL * sizeof(float);
    int*   top_ws  = (int*)(ws + off);   off += (size_t)BB * HH * NT * sizeof(int);
    float* mean_ws = (float*)(ws + off); off += (size_t)BB * HH * DD * sizeof(float);
    float* upd_ws  = (float*)(ws + off); off += (size_t)BB * HH * NT * DD * sizeof(float);
    float* base_ws = (float*)(ws + off); off += (size_t)BB * EE * sizeof(float);

    // K1: QKV projections
    dim3 g1(EE / PBN, (BB * LL) / PBM, 3);
    proj_kernel<<<g1, 256, 0, stream>>>(query, key, value, Wq, Wk, Wv, bq, bk, bv,
                                        q_ws, k_ws, v_ws);
    // K2: mean of V
    meanv_kernel<<<BB * HH, 256, 0, stream>>>(v_ws, mean_ws);
    // K3: sparsity measure
    dim3 g3(BB * HH, LL / 4);
    measure_kernel<<<g3, 256, 0, stream>>>(q_ws, k_ws, idxs, M_ws);
    // K4: top-40
    topk_kernel<<<BB * HH, 256, 0, stream>>>(M_ws, top_ws);
    // K5: attention on selected rows
    attn_kernel<<<BB * HH * NT, 256, 0, stream>>>(q_ws, k_ws, v_ws, top_ws, upd_ws);
    // K6: output projection (base + broadcast + corrections)
    base_kernel<<<(BB * EE) / 4, 256, 0, stream>>>(mean_ws, Wo, bo, base_ws);
    bcast_kernel<<<(BB * LL * EE) / (256 * 4), 256, 0, stream>>>(base_ws, out);
    corr_kernel<<<BB * HH * NT, 256, 0, stream>>>(upd_ws, mean_ws, top_ws, Wo, out);
}

// Round 3
// 625.675 us; speedup vs baseline: 1.2009x; 1.2009x over previous
//
#include <hip/hip_runtime.h>
#include <hip/hip_bf16.h>
#include <math.h>

// Problem constants (fixed by reference)
constexpr int BB = 4;
constexpr int LL = 2048;
constexpr int EE = 512;
constexpr int HH = 8;
constexpr int DD = 64;
constexpr int UU = 40;    // sample count
constexpr int NT = 40;    // n_top
constexpr float NEG_INF = -3.0e38f;

// ---------------------------------------------------------------------------
// K1: fused QKV projection GEMM (NT layout: out[m,n] = sum_k X[m,k]*W[n,k] + b[n])
// M=8192, N=512, K=512. BM=BN=128, BK=16, 256 threads, 8x8 microtile.
// Output written directly in (B,H,L,D) layout.
// ---------------------------------------------------------------------------
constexpr int PBM = 128, PBN = 128, PBK = 16;

__global__ __launch_bounds__(256) void proj_kernel(
    const float* __restrict__ Xq, const float* __restrict__ Xk, const float* __restrict__ Xv,
    const float* __restrict__ Wq, const float* __restrict__ Wk, const float* __restrict__ Wv,
    const float* __restrict__ bq, const float* __restrict__ bk, const float* __restrict__ bv,
    float* __restrict__ Oq, float* __restrict__ Ok, float* __restrict__ Ov)
{
    const float* X; const float* W; const float* bias; float* O;
    if (blockIdx.z == 0)      { X = Xq; W = Wq; bias = bq; O = Oq; }
    else if (blockIdx.z == 1) { X = Xk; W = Wk; bias = bk; O = Ok; }
    else                      { X = Xv; W = Wv; bias = bv; O = Ov; }

    __shared__ float As[PBK][PBM];
    __shared__ float Bs[PBK][PBN];

    const int tid  = threadIdx.x;
    const int lane = tid & 63;
    const int wv   = tid >> 6;
    // wave-quadrant map: within a wave tx spans 8 values (2-way LDS alias, free),
    // ty spans 8 values (broadcast).
    const int tx = ((wv & 1) << 3) + (lane & 7);   // 0..15
    const int ty = ((wv >> 1) << 3) + (lane >> 3); // 0..15

    const int m0 = blockIdx.y * PBM;
    const int n0 = blockIdx.x * PBN;

    const int lrow = tid >> 1;        // 0..127
    const int lcol = (tid & 1) * 8;   // 0 or 8

    float acc[8][8];
#pragma unroll
    for (int i = 0; i < 8; i++)
#pragma unroll
        for (int j = 0; j < 8; j++) acc[i][j] = 0.0f;

    const float* Arow = X + (size_t)(m0 + lrow) * EE + lcol;
    const float* Brow = W + (size_t)(n0 + lrow) * EE + lcol;

    for (int kt = 0; kt < EE; kt += PBK) {
        float4 a0 = *(const float4*)(Arow + kt);
        float4 a1 = *(const float4*)(Arow + kt + 4);
        float4 b0 = *(const float4*)(Brow + kt);
        float4 b1 = *(const float4*)(Brow + kt + 4);
        __syncthreads();
        As[lcol + 0][lrow] = a0.x; As[lcol + 1][lrow] = a0.y;
        As[lcol + 2][lrow] = a0.z; As[lcol + 3][lrow] = a0.w;
        As[lcol + 4][lrow] = a1.x; As[lcol + 5][lrow] = a1.y;
        As[lcol + 6][lrow] = a1.z; As[lcol + 7][lrow] = a1.w;
        Bs[lcol + 0][lrow] = b0.x; Bs[lcol + 1][lrow] = b0.y;
        Bs[lcol + 2][lrow] = b0.z; Bs[lcol + 3][lrow] = b0.w;
        Bs[lcol + 4][lrow] = b1.x; Bs[lcol + 5][lrow] = b1.y;
        Bs[lcol + 6][lrow] = b1.z; Bs[lcol + 7][lrow] = b1.w;
        __syncthreads();
#pragma unroll
        for (int k = 0; k < PBK; k++) {
            float4 av0 = *(const float4*)&As[k][ty * 8];
            float4 av1 = *(const float4*)&As[k][ty * 8 + 4];
            float4 bv0 = *(const float4*)&Bs[k][tx * 8];
            float4 bv1 = *(const float4*)&Bs[k][tx * 8 + 4];
            float a[8] = {av0.x, av0.y, av0.z, av0.w, av1.x, av1.y, av1.z, av1.w};
            float b[8] = {bv0.x, bv0.y, bv0.z, bv0.w, bv1.x, bv1.y, bv1.z, bv1.w};
#pragma unroll
            for (int i = 0; i < 8; i++)
#pragma unroll
                for (int j = 0; j < 8; j++) acc[i][j] += a[i] * b[j];
        }
    }

    // epilogue: add bias, write to (B,H,L,D)
    const int hh = (n0 >> 6) + ((tx * 8) >> 6);
    const int dd = (tx * 8) & 63;
    float bias8[8];
#pragma unroll
    for (int j = 0; j < 8; j++) bias8[j] = bias[n0 + tx * 8 + j];

#pragma unroll
    for (int r = 0; r < 8; r++) {
        int m  = m0 + ty * 8 + r;
        int b_ = m >> 11;
        int l_ = m & (LL - 1);
        float* orow = O + (((size_t)(b_ * HH + hh) * LL + l_) << 6) + dd;
        float4 o0 = {acc[r][0] + bias8[0], acc[r][1] + bias8[1],
                     acc[r][2] + bias8[2], acc[r][3] + bias8[3]};
        float4 o1 = {acc[r][4] + bias8[4], acc[r][5] + bias8[5],
                     acc[r][6] + bias8[6], acc[r][7] + bias8[7]};
        *(float4*)(orow)     = o0;
        *(float4*)(orow + 4) = o1;
    }
}

// ---------------------------------------------------------------------------
// K2: mean of V over L per (b,h)
// ---------------------------------------------------------------------------
__global__ __launch_bounds__(256) void meanv_kernel(const float* __restrict__ v,
                                                    float* __restrict__ mean_v)
{
    int bh = blockIdx.x;
    int d  = threadIdx.x & 63;
    int g  = threadIdx.x >> 6;
    const float* base = v + (size_t)bh * LL * DD;
    float acc = 0.0f;
    for (int l = g; l < LL; l += 4) acc += base[(size_t)l * DD + d];
    __shared__ float red[4][DD];
    red[g][d] = acc;
    __syncthreads();
    if (g == 0) {
        float s = red[0][d] + red[1][d] + red[2][d] + red[3][d];
        mean_v[bh * DD + d] = s * (1.0f / (float)LL);
    }
}

// ---------------------------------------------------------------------------
// K3: sparsity measure M[b,h,l] = max_s(q.k_sample) - sum_s(q.k_sample)/L
// One wave per (b,h,l). Lane map: 8 samples x 8 d-chunks.
// Each lane: 32B vector load of its sample's k-row chunk, 8 FMAs, 3-step
// in-group xor reduce -> 8 sample dots in parallel. 5 iterations cover U=40.
// Cross-group reduce (xor bits 3-5) visits ONE lane per group for fixed chunk
// -> sum is the exact 40-sample total (NOT 8x replicated).
// ---------------------------------------------------------------------------
__global__ __launch_bounds__(256) void measure_kernel(const float* __restrict__ q,
                                                      const float* __restrict__ k,
                                                      const int* __restrict__ idx_sample,
                                                      float* __restrict__ M)
{
    int bh   = blockIdx.x;
    int lane = threadIdx.x & 63;
    int wv   = threadIdx.x >> 6;
    int l    = blockIdx.y * 4 + wv;
    int s8   = lane >> 3;   // sample slot 0..7
    int c    = lane & 7;    // d-chunk 0..7

    const float* qrow = q + ((size_t)bh * LL + l) * DD + c * 8;
    float4 q0 = *(const float4*)(qrow);
    float4 q1 = *(const float4*)(qrow + 4);

    const float* kbase = k + (size_t)bh * LL * DD;
    const int*   irow  = idx_sample + l * UU;

    float mx = NEG_INF, sum = 0.0f;
#pragma unroll
    for (int it = 0; it < UU; it += 8) {
        int ki = irow[it + s8];
        const float* krow = kbase + (size_t)ki * DD + c * 8;
        float4 k0 = *(const float4*)(krow);
        float4 k1 = *(const float4*)(krow + 4);
        float p = q0.x*k0.x + q0.y*k0.y + q0.z*k0.z + q0.w*k0.w
                + q1.x*k1.x + q1.y*k1.y + q1.z*k1.z + q1.w*k1.w;
        // reduce over the 8 d-chunks within the sample group
        p += __shfl_xor(p, 1, 64);
        p += __shfl_xor(p, 2, 64);
        p += __shfl_xor(p, 4, 64);
        mx = fmaxf(mx, p);
        sum += p;
    }
    // reduce across the 8 sample groups (one lane per group at fixed c)
    mx  = fmaxf(mx, __shfl_xor(mx, 8, 64));
    sum += __shfl_xor(sum, 8, 64);
    mx  = fmaxf(mx, __shfl_xor(mx, 16, 64));
    sum += __shfl_xor(sum, 16, 64);
    mx  = fmaxf(mx, __shfl_xor(mx, 32, 64));
    sum += __shfl_xor(sum, 32, 64);

    if (lane == 0) M[bh * LL + l] = mx - sum * (1.0f / (float)LL);
}

// ---------------------------------------------------------------------------
// K4: top-40 indices of M per (b,h) (iterative masked max, ties -> lowest idx)
// ---------------------------------------------------------------------------
__global__ __launch_bounds__(256) void topk_kernel(const float* __restrict__ M,
                                                   int* __restrict__ top)
{
    int bh  = blockIdx.x;
    int tid = threadIdx.x;
    __shared__ float vals[LL];
    __shared__ float rv[256];
    __shared__ int   ri[256];

    for (int i = tid; i < LL; i += 256) vals[i] = M[bh * LL + i];
    __syncthreads();

    for (int it = 0; it < NT; it++) {
        float bv = NEG_INF;
        int   bi = 0x7fffffff;
        for (int i = tid; i < LL; i += 256) {
            float vvv = vals[i];
            if (vvv > bv || (vvv == bv && i < bi)) { bv = vvv; bi = i; }
        }
        rv[tid] = bv; ri[tid] = bi;
        __syncthreads();
        for (int s = 128; s > 0; s >>= 1) {
            if (tid < s) {
                float ov = rv[tid + s]; int oi = ri[tid + s];
                if (ov > rv[tid] || (ov == rv[tid] && oi < ri[tid])) {
                    rv[tid] = ov; ri[tid] = oi;
                }
            }
            __syncthreads();
        }
        if (tid == 0) { top[bh * NT + it] = ri[0]; vals[ri[0]] = NEG_INF; }
        __syncthreads();
    }
}

// ---------------------------------------------------------------------------
// K5: full attention for the 40 selected rows per (b,h):
//     scores = q_sel . k (2048), softmax, upd = attn @ v
// One block per (b,h,u).
// ---------------------------------------------------------------------------
__global__ __launch_bounds__(256) void attn_kernel(const float* __restrict__ q,
                                                   const float* __restrict__ k,
                                                   const float* __restrict__ v,
                                                   const int* __restrict__ top,
                                                   float* __restrict__ upd)
{
    int bhu = blockIdx.x;
    int bh  = bhu / NT;
    int tid = threadIdx.x;

    __shared__ float qs[DD];
    __shared__ float sc[LL];
    __shared__ float red[256];
    __shared__ float pv[4][DD];

    int l = top[bhu];
    if (tid < DD) qs[tid] = q[((size_t)bh * LL + l) * DD + tid];
    __syncthreads();

    const float* kbase = k + (size_t)bh * LL * DD;
    float myscore[8];
    float lmax = NEG_INF;
#pragma unroll
    for (int j = 0; j < 8; j++) {
        int kk = tid + j * 256;
        const float* krow = kbase + (size_t)kk * DD;
        float acc = 0.0f;
#pragma unroll
        for (int d4 = 0; d4 < 16; d4++) {
            float4 kv = *(const float4*)(krow + d4 * 4);
            float4 qv = *(const float4*)(qs + d4 * 4);
            acc += kv.x * qv.x + kv.y * qv.y + kv.z * qv.z + kv.w * qv.w;
        }
        myscore[j] = acc;
        lmax = fmaxf(lmax, acc);
    }
    red[tid] = lmax;
    __syncthreads();
    for (int s = 128; s > 0; s >>= 1) {
        if (tid < s) red[tid] = fmaxf(red[tid], red[tid + s]);
        __syncthreads();
    }
    float gmax = red[0];
    __syncthreads();

    float lsum = 0.0f;
#pragma unroll
    for (int j = 0; j < 8; j++) {
        float e = __expf(myscore[j] - gmax);
        sc[tid + j * 256] = e;
        lsum += e;
    }
    red[tid] = lsum;
    __syncthreads();
    for (int s = 128; s > 0; s >>= 1) {
        if (tid < s) red[tid] += red[tid + s];
        __syncthreads();
    }
    float inv = 1.0f / red[0];

    // PV: wave w handles keys [w*512, w*512+512); lane = d
    int lane = tid & 63, wv = tid >> 6;
    const float* vbase = v + (size_t)bh * LL * DD;
    float acc = 0.0f;
    for (int kk = wv * 512; kk < wv * 512 + 512; kk++) {
        acc += sc[kk] * vbase[(size_t)kk * DD + lane];
    }
    pv[wv][lane] = acc;
    __syncthreads();
    if (tid < DD) {
        float s = pv[0][tid] + pv[1][tid] + pv[2][tid] + pv[3][tid];
        upd[(size_t)bhu * DD + tid] = s * inv;
    }
}

// ---------------------------------------------------------------------------
// K6a: base output row per batch: base[b,e] = meanctx[b,:] . Wo[e,:] + bo[e]
// One wave per (b,e).
// ---------------------------------------------------------------------------
__global__ __launch_bounds__(256) void base_kernel(const float* __restrict__ mean_v,
                                                   const float* __restrict__ Wo,
                                                   const float* __restrict__ bo,
                                                   float* __restrict__ base)
{
    int lane = threadIdx.x & 63, wv = threadIdx.x >> 6;
    int be = blockIdx.x * 4 + wv;
    int b  = be >> 9;
    int e  = be & (EE - 1);
    const float* mrow = mean_v + b * EE;   // (b,h,d) contiguous = concat over heads
    const float* wrow = Wo + (size_t)e * EE;
    float acc = 0.0f;
#pragma unroll
    for (int j = 0; j < 8; j++) acc += mrow[lane + j * 64] * wrow[lane + j * 64];
#pragma unroll
    for (int off = 32; off > 0; off >>= 1) acc += __shfl_down(acc, off, 64);
    if (lane == 0) base[be] = acc + bo[e];
}

// ---------------------------------------------------------------------------
// K6b: broadcast base row to all l: out[b,l,:] = base[b,:]
// ---------------------------------------------------------------------------
__global__ __launch_bounds__(256) void bcast_kernel(const float* __restrict__ base,
                                                    float* __restrict__ out)
{
    size_t fi = ((size_t)blockIdx.x * 256 + threadIdx.x) * 4;
    int b  = (int)(fi >> 20);          // / (2048*512)
    int e4 = (int)(fi & (EE - 1));
    float4 val = *(const float4*)(base + b * EE + e4);
    *(float4*)(out + fi) = val;
}

// ---------------------------------------------------------------------------
// K6c: corrections: out[b,l_sel,:] += (upd - mean_v) . Wo_h^T   (atomic)
// One block per (b,h,u).
// ---------------------------------------------------------------------------
__global__ __launch_bounds__(256) void corr_kernel(const float* __restrict__ upd,
                                                   const float* __restrict__ mean_v,
                                                   const int* __restrict__ top,
                                                   const float* __restrict__ Wo,
                                                   float* __restrict__ out)
{
    int bhu = blockIdx.x;
    int bh  = bhu / NT;
    int h   = bh & (HH - 1);
    int b   = bh >> 3;
    int tid = threadIdx.x;
    int l   = top[bhu];

    __shared__ float delta[DD];
    if (tid < DD) delta[tid] = upd[(size_t)bhu * DD + tid] - mean_v[bh * DD + tid];
    __syncthreads();

    float* orow = out + ((size_t)(b * LL + l)) * EE;
#pragma unroll
    for (int rep = 0; rep < 2; rep++) {
        int e = tid + rep * 256;
        const float* wrow = Wo + (size_t)e * EE + h * DD;
        float acc = 0.0f;
#pragma unroll
        for (int d = 0; d < DD; d++) acc += delta[d] * wrow[d];
        atomicAdd(orow + e, acc);
    }
}

// ---------------------------------------------------------------------------
extern "C" void kernel_launch(void* const* d_in, const int* in_sizes, int n_in,
                              void* d_out, int out_size, void* d_ws, size_t ws_size,
                              hipStream_t stream)
{
    const float* query = (const float*)d_in[0];
    const float* key   = (const float*)d_in[1];
    const float* value = (const float*)d_in[2];
    const int*   idxs  = (const int*)d_in[3];
    const float* Wq = (const float*)d_in[4];
    const float* bq = (const float*)d_in[5];
    const float* Wk = (const float*)d_in[6];
    const float* bk = (const float*)d_in[7];
    const float* Wv = (const float*)d_in[8];
    const float* bv = (const float*)d_in[9];
    const float* Wo = (const float*)d_in[10];
    const float* bo = (const float*)d_in[11];
    float* out = (float*)d_out;

    // workspace layout
    char* ws = (char*)d_ws;
    size_t off = 0;
    const size_t qkv_bytes = (size_t)BB * HH * LL * DD * sizeof(float); // 16 MB each
    float* q_ws = (float*)(ws + off); off += qkv_bytes;
    float* k_ws = (float*)(ws + off); off += qkv_bytes;
    float* v_ws = (float*)(ws + off); off += qkv_bytes;
    float* M_ws    = (float*)(ws + off); off += (size_t)BB * HH * LL * sizeof(float);
    int*   top_ws  = (int*)(ws + off);   off += (size_t)BB * HH * NT * sizeof(int);
    float* mean_ws = (float*)(ws + off); off += (size_t)BB * HH * DD * sizeof(float);
    float* upd_ws  = (float*)(ws + off); off += (size_t)BB * HH * NT * DD * sizeof(float);
    float* base_ws = (float*)(ws + off); off += (size_t)BB * EE * sizeof(float);

    // K1: QKV projections
    dim3 g1(EE / PBN, (BB * LL) / PBM, 3);
    proj_kernel<<<g1, 256, 0, stream>>>(query, key, value, Wq, Wk, Wv, bq, bk, bv,
                                        q_ws, k_ws, v_ws);
    // K2: mean of V
    meanv_kernel<<<BB * HH, 256, 0, stream>>>(v_ws, mean_ws);
    // K3: sparsity measure
    dim3 g3(BB * HH, LL / 4);
    measure_kernel<<<g3, 256, 0, stream>>>(q_ws, k_ws, idxs, M_ws);
    // K4: top-40
    topk_kernel<<<BB * HH, 256, 0, stream>>>(M_ws, top_ws);
    // K5: attention on selected rows
    attn_kernel<<<BB * HH * NT, 256, 0, stream>>>(q_ws, k_ws, v_ws, top_ws, upd_ws);
    // K6: output projection (base + broadcast + corrections)
    base_kernel<<<(BB * EE) / 4, 256, 0, stream>>>(mean_ws, Wo, bo, base_ws);
    bcast_kernel<<<(BB * LL * EE) / (256 * 4), 256, 0, stream>>>(base_ws, out);
    corr_kernel<<<BB * HH * NT, 256, 0, stream>>>(upd_ws, mean_ws, top_ws, Wo, out);
}

// Round 4
// 548.718 us; speedup vs baseline: 1.3693x; 1.1402x over previous
//
#include <hip/hip_runtime.h>
#include <hip/hip_bf16.h>
#include <math.h>

// Problem constants (fixed by reference)
constexpr int BB = 4;
constexpr int LL = 2048;
constexpr int EE = 512;
constexpr int HH = 8;
constexpr int DD = 64;
constexpr int UU = 40;    // sample count
constexpr int NT = 40;    // n_top
constexpr float NEG_INF = -3.0e38f;

typedef __attribute__((ext_vector_type(8))) short bf8_t;  // 8 bf16 (4 VGPR)
typedef __attribute__((ext_vector_type(4))) float f4_t;   // MFMA C/D frag

// ---------------------------------------------------------------------------
// K1: fused QKV projection via split-bf16 MFMA.
// out[m,n] = sum_k X[m,k]*W[n,k] + b[n];  M=8192, N=512, K=512 per projection.
// f32 = hi(RNE bf16) + mid(trunc bf16) + lo(trunc bf16); 6 products
// (hh,hm,mh,hl,lh,mm) -> error ~2^-21 relative, f32-equivalent for top-k.
// Tile 128x128x32, 4 waves (2x2 of 64x64), 16x16x32 bf16 MFMA.
// LDS 48 KB: 3 splits x [128 rows x 32 k] bf16 for A and B, XOR-swizzled
// chunks (16B): phys_c = c ^ (row&3) ^ ((row>>2)&3) -> 2-way banking (free).
// ---------------------------------------------------------------------------
__device__ __forceinline__ void split3(float x, uint& h, uint& m, uint& l)
{
    uint  xb = __float_as_uint(x);
    uint  hb = (xb + 0x7fffu + ((xb >> 16) & 1u)) & 0xffff0000u;  // RNE bf16
    float r  = x - __uint_as_float(hb);
    uint  mb = __float_as_uint(r) & 0xffff0000u;                  // trunc
    float r2 = r - __uint_as_float(mb);
    h = hb >> 16; m = mb >> 16; l = __float_as_uint(r2) >> 16;    // trunc
}

__device__ __forceinline__ int swz(int row, int c)
{
    return row * 64 + (((c ^ row ^ (row >> 2)) & 3) << 4);
}

__global__ __launch_bounds__(256, 3) void proj_kernel(
    const float* __restrict__ Xq, const float* __restrict__ Xk, const float* __restrict__ Xv,
    const float* __restrict__ Wq, const float* __restrict__ Wk, const float* __restrict__ Wv,
    const float* __restrict__ bq, const float* __restrict__ bk, const float* __restrict__ bv,
    float* __restrict__ Oq, float* __restrict__ Ok, float* __restrict__ Ov)
{
    const float* X; const float* W; const float* bias; float* O;
    if (blockIdx.z == 0)      { X = Xq; W = Wq; bias = bq; O = Oq; }
    else if (blockIdx.z == 1) { X = Xk; W = Wk; bias = bk; O = Ok; }
    else                      { X = Xv; W = Wv; bias = bv; O = Ov; }

    __shared__ char ldsmem[49152];   // A: 3 x 8192 B, B: 3 x 8192 B
    char* const LA = ldsmem;
    char* const LB = ldsmem + 24576;

    const int tid  = threadIdx.x;
    const int lane = tid & 63;
    const int wave = tid >> 6;
    const int m0 = blockIdx.y * 128;
    const int n0 = blockIdx.x * 128;

    // staging map: thread t handles row t>>1, k-half (t&1)*16 (16 f32)
    const int srow  = tid >> 1;
    const int shalf = tid & 1;
    const int w0 = swz(srow, shalf * 2);
    const int w1 = swz(srow, shalf * 2 + 1);
    const float* Aptr = X + (size_t)(m0 + srow) * EE + shalf * 16;
    const float* Bptr = W + (size_t)(n0 + srow) * EE + shalf * 16;

    // fragment-read swizzle (row&3 == lane&3, (row>>2)&3 == (lane>>2)&3)
    const int rxor = ((((lane >> 4) ^ lane ^ (lane >> 2)) & 3) << 4);
    const int arow = (wave >> 1) * 64 + (lane & 15);
    const int brow = (wave & 1) * 64 + (lane & 15);

    f4_t acc[4][4];
#pragma unroll
    for (int i = 0; i < 4; i++)
#pragma unroll
        for (int j = 0; j < 4; j++) acc[i][j] = (f4_t)0.0f;

    for (int kt = 0; kt < EE; kt += 32) {
        // ---- load + split 16 A floats and 16 B floats ----
        float fa[16], fb[16];
#pragma unroll
        for (int q = 0; q < 4; q++) {
            *(float4*)(fa + q * 4) = *(const float4*)(Aptr + kt + q * 4);
            *(float4*)(fb + q * 4) = *(const float4*)(Bptr + kt + q * 4);
        }
        uint ahu[8], amu[8], alu[8], bhu[8], bmu[8], blu[8];
#pragma unroll
        for (int p = 0; p < 8; p++) {
            uint h0, m0_, l0, h1, m1_, l1;
            split3(fa[2 * p], h0, m0_, l0);
            split3(fa[2 * p + 1], h1, m1_, l1);
            ahu[p] = h0 | (h1 << 16); amu[p] = m0_ | (m1_ << 16); alu[p] = l0 | (l1 << 16);
            split3(fb[2 * p], h0, m0_, l0);
            split3(fb[2 * p + 1], h1, m1_, l1);
            bhu[p] = h0 | (h1 << 16); bmu[p] = m0_ | (m1_ << 16); blu[p] = l0 | (l1 << 16);
        }
        __syncthreads();   // previous tile's readers done
        *(uint4*)(LA +      0 + w0) = make_uint4(ahu[0], ahu[1], ahu[2], ahu[3]);
        *(uint4*)(LA +      0 + w1) = make_uint4(ahu[4], ahu[5], ahu[6], ahu[7]);
        *(uint4*)(LA +   8192 + w0) = make_uint4(amu[0], amu[1], amu[2], amu[3]);
        *(uint4*)(LA +   8192 + w1) = make_uint4(amu[4], amu[5], amu[6], amu[7]);
        *(uint4*)(LA +  16384 + w0) = make_uint4(alu[0], alu[1], alu[2], alu[3]);
        *(uint4*)(LA +  16384 + w1) = make_uint4(alu[4], alu[5], alu[6], alu[7]);
        *(uint4*)(LB +      0 + w0) = make_uint4(bhu[0], bhu[1], bhu[2], bhu[3]);
        *(uint4*)(LB +      0 + w1) = make_uint4(bhu[4], bhu[5], bhu[6], bhu[7]);
        *(uint4*)(LB +   8192 + w0) = make_uint4(bmu[0], bmu[1], bmu[2], bmu[3]);
        *(uint4*)(LB +   8192 + w1) = make_uint4(bmu[4], bmu[5], bmu[6], bmu[7]);
        *(uint4*)(LB +  16384 + w0) = make_uint4(blu[0], blu[1], blu[2], blu[3]);
        *(uint4*)(LB +  16384 + w1) = make_uint4(blu[4], blu[5], blu[6], blu[7]);
        __syncthreads();   // tile ready

        // ---- MFMA: 4x4 frags x 6 split-products ----
        bf8_t af[4][3];
#pragma unroll
        for (int i = 0; i < 4; i++) {
            const int ro = (arow + i * 16) * 64 + rxor;
            af[i][0] = *(const bf8_t*)(LA +     0 + ro);
            af[i][1] = *(const bf8_t*)(LA +  8192 + ro);
            af[i][2] = *(const bf8_t*)(LA + 16384 + ro);
        }
#pragma unroll
        for (int j = 0; j < 4; j++) {
            const int ro = (brow + j * 16) * 64 + rxor;
            bf8_t bh_ = *(const bf8_t*)(LB +     0 + ro);
            bf8_t bm_ = *(const bf8_t*)(LB +  8192 + ro);
            bf8_t bl_ = *(const bf8_t*)(LB + 16384 + ro);
#pragma unroll
            for (int i = 0; i < 4; i++) {
                f4_t c = acc[i][j];
                c = __builtin_amdgcn_mfma_f32_16x16x32_bf16(af[i][0], bh_, c, 0, 0, 0); // hh
                c = __builtin_amdgcn_mfma_f32_16x16x32_bf16(af[i][0], bm_, c, 0, 0, 0); // hm
                c = __builtin_amdgcn_mfma_f32_16x16x32_bf16(af[i][1], bh_, c, 0, 0, 0); // mh
                c = __builtin_amdgcn_mfma_f32_16x16x32_bf16(af[i][0], bl_, c, 0, 0, 0); // hl
                c = __builtin_amdgcn_mfma_f32_16x16x32_bf16(af[i][2], bh_, c, 0, 0, 0); // lh
                c = __builtin_amdgcn_mfma_f32_16x16x32_bf16(af[i][1], bm_, c, 0, 0, 0); // mm
                acc[i][j] = c;
            }
        }
    }

    // ---- epilogue: bias + scatter to (B,H,L,D) ----
#pragma unroll
    for (int j = 0; j < 4; j++) {
        const int n  = n0 + (wave & 1) * 64 + j * 16 + (lane & 15);
        const float bn = bias[n];
        const int h_ = n >> 6, d_ = n & 63;
#pragma unroll
        for (int i = 0; i < 4; i++) {
            const int mb = m0 + (wave >> 1) * 64 + i * 16 + ((lane >> 4) << 2);
#pragma unroll
            for (int r = 0; r < 4; r++) {
                const int m  = mb + r;
                const int b_ = m >> 11;
                const int l_ = m & (LL - 1);
                O[(((size_t)(b_ * HH + h_) * LL + l_) << 6) + d_] = acc[i][j][r] + bn;
            }
        }
    }
}

// ---------------------------------------------------------------------------
// K2: mean of V over L per (b,h)
// ---------------------------------------------------------------------------
__global__ __launch_bounds__(256) void meanv_kernel(const float* __restrict__ v,
                                                    float* __restrict__ mean_v)
{
    int bh = blockIdx.x;
    int d  = threadIdx.x & 63;
    int g  = threadIdx.x >> 6;
    const float* base = v + (size_t)bh * LL * DD;
    float acc = 0.0f;
    for (int l = g; l < LL; l += 4) acc += base[(size_t)l * DD + d];
    __shared__ float red[4][DD];
    red[g][d] = acc;
    __syncthreads();
    if (g == 0) {
        float s = red[0][d] + red[1][d] + red[2][d] + red[3][d];
        mean_v[bh * DD + d] = s * (1.0f / (float)LL);
    }
}

// ---------------------------------------------------------------------------
// K3: sparsity measure M[b,h,l] = max_s(q.k_sample) - sum_s(q.k_sample)/L
// One wave per (b,h,l). Lane map: 8 samples x 8 d-chunks.
// ---------------------------------------------------------------------------
__global__ __launch_bounds__(256) void measure_kernel(const float* __restrict__ q,
                                                      const float* __restrict__ k,
                                                      const int* __restrict__ idx_sample,
                                                      float* __restrict__ M)
{
    int bh   = blockIdx.x;
    int lane = threadIdx.x & 63;
    int wv   = threadIdx.x >> 6;
    int l    = blockIdx.y * 4 + wv;
    int s8   = lane >> 3;   // sample slot 0..7
    int c    = lane & 7;    // d-chunk 0..7

    const float* qrow = q + ((size_t)bh * LL + l) * DD + c * 8;
    float4 q0 = *(const float4*)(qrow);
    float4 q1 = *(const float4*)(qrow + 4);

    const float* kbase = k + (size_t)bh * LL * DD;
    const int*   irow  = idx_sample + l * UU;

    float mx = NEG_INF, sum = 0.0f;
#pragma unroll
    for (int it = 0; it < UU; it += 8) {
        int ki = irow[it + s8];
        const float* krow = kbase + (size_t)ki * DD + c * 8;
        float4 k0 = *(const float4*)(krow);
        float4 k1 = *(const float4*)(krow + 4);
        float p = q0.x*k0.x + q0.y*k0.y + q0.z*k0.z + q0.w*k0.w
                + q1.x*k1.x + q1.y*k1.y + q1.z*k1.z + q1.w*k1.w;
        p += __shfl_xor(p, 1, 64);
        p += __shfl_xor(p, 2, 64);
        p += __shfl_xor(p, 4, 64);
        mx = fmaxf(mx, p);
        sum += p;
    }
    mx  = fmaxf(mx, __shfl_xor(mx, 8, 64));
    sum += __shfl_xor(sum, 8, 64);
    mx  = fmaxf(mx, __shfl_xor(mx, 16, 64));
    sum += __shfl_xor(sum, 16, 64);
    mx  = fmaxf(mx, __shfl_xor(mx, 32, 64));
    sum += __shfl_xor(sum, 32, 64);

    if (lane == 0) M[bh * LL + l] = mx - sum * (1.0f / (float)LL);
}

// ---------------------------------------------------------------------------
// K4: top-40 indices of M per (b,h) (iterative masked max, ties -> lowest idx)
// ---------------------------------------------------------------------------
__global__ __launch_bounds__(256) void topk_kernel(const float* __restrict__ M,
                                                   int* __restrict__ top)
{
    int bh  = blockIdx.x;
    int tid = threadIdx.x;
    __shared__ float vals[LL];
    __shared__ float rv[256];
    __shared__ int   ri[256];

    for (int i = tid; i < LL; i += 256) vals[i] = M[bh * LL + i];
    __syncthreads();

    for (int it = 0; it < NT; it++) {
        float bv = NEG_INF;
        int   bi = 0x7fffffff;
        for (int i = tid; i < LL; i += 256) {
            float vvv = vals[i];
            if (vvv > bv || (vvv == bv && i < bi)) { bv = vvv; bi = i; }
        }
        rv[tid] = bv; ri[tid] = bi;
        __syncthreads();
        for (int s = 128; s > 0; s >>= 1) {
            if (tid < s) {
                float ov = rv[tid + s]; int oi = ri[tid + s];
                if (ov > rv[tid] || (ov == rv[tid] && oi < ri[tid])) {
                    rv[tid] = ov; ri[tid] = oi;
                }
            }
            __syncthreads();
        }
        if (tid == 0) { top[bh * NT + it] = ri[0]; vals[ri[0]] = NEG_INF; }
        __syncthreads();
    }
}

// ---------------------------------------------------------------------------
// K5: full attention for the 40 selected rows per (b,h):
//     scores = q_sel . k (2048), softmax, upd = attn @ v
// One block per (b,h,u).
// ---------------------------------------------------------------------------
__global__ __launch_bounds__(256) void attn_kernel(const float* __restrict__ q,
                                                   const float* __restrict__ k,
                                                   const float* __restrict__ v,
                                                   const int* __restrict__ top,
                                                   float* __restrict__ upd)
{
    int bhu = blockIdx.x;
    int bh  = bhu / NT;
    int tid = threadIdx.x;

    __shared__ float qs[DD];
    __shared__ float sc[LL];
    __shared__ float red[256];
    __shared__ float pv[4][DD];

    int l = top[bhu];
    if (tid < DD) qs[tid] = q[((size_t)bh * LL + l) * DD + tid];
    __syncthreads();

    const float* kbase = k + (size_t)bh * LL * DD;
    float myscore[8];
    float lmax = NEG_INF;
#pragma unroll
    for (int j = 0; j < 8; j++) {
        int kk = tid + j * 256;
        const float* krow = kbase + (size_t)kk * DD;
        float acc = 0.0f;
#pragma unroll
        for (int d4 = 0; d4 < 16; d4++) {
            float4 kv = *(const float4*)(krow + d4 * 4);
            float4 qv = *(const float4*)(qs + d4 * 4);
            acc += kv.x * qv.x + kv.y * qv.y + kv.z * qv.z + kv.w * qv.w;
        }
        myscore[j] = acc;
        lmax = fmaxf(lmax, acc);
    }
    red[tid] = lmax;
    __syncthreads();
    for (int s = 128; s > 0; s >>= 1) {
        if (tid < s) red[tid] = fmaxf(red[tid], red[tid + s]);
        __syncthreads();
    }
    float gmax = red[0];
    __syncthreads();

    float lsum = 0.0f;
#pragma unroll
    for (int j = 0; j < 8; j++) {
        float e = __expf(myscore[j] - gmax);
        sc[tid + j * 256] = e;
        lsum += e;
    }
    red[tid] = lsum;
    __syncthreads();
    for (int s = 128; s > 0; s >>= 1) {
        if (tid < s) red[tid] += red[tid + s];
        __syncthreads();
    }
    float inv = 1.0f / red[0];

    int lane = tid & 63, wv = tid >> 6;
    const float* vbase = v + (size_t)bh * LL * DD;
    float acc = 0.0f;
    for (int kk = wv * 512; kk < wv * 512 + 512; kk++) {
        acc += sc[kk] * vbase[(size_t)kk * DD + lane];
    }
    pv[wv][lane] = acc;
    __syncthreads();
    if (tid < DD) {
        float s = pv[0][tid] + pv[1][tid] + pv[2][tid] + pv[3][tid];
        upd[(size_t)bhu * DD + tid] = s * inv;
    }
}

// ---------------------------------------------------------------------------
// K6a: base output row per batch: base[b,e] = meanctx[b,:] . Wo[e,:] + bo[e]
// ---------------------------------------------------------------------------
__global__ __launch_bounds__(256) void base_kernel(const float* __restrict__ mean_v,
                                                   const float* __restrict__ Wo,
                                                   const float* __restrict__ bo,
                                                   float* __restrict__ base)
{
    int lane = threadIdx.x & 63, wv = threadIdx.x >> 6;
    int be = blockIdx.x * 4 + wv;
    int b  = be >> 9;
    int e  = be & (EE - 1);
    const float* mrow = mean_v + b * EE;
    const float* wrow = Wo + (size_t)e * EE;
    float acc = 0.0f;
#pragma unroll
    for (int j = 0; j < 8; j++) acc += mrow[lane + j * 64] * wrow[lane + j * 64];
#pragma unroll
    for (int off = 32; off > 0; off >>= 1) acc += __shfl_down(acc, off, 64);
    if (lane == 0) base[be] = acc + bo[e];
}

// ---------------------------------------------------------------------------
// K6b: broadcast base row to all l
// ---------------------------------------------------------------------------
__global__ __launch_bounds__(256) void bcast_kernel(const float* __restrict__ base,
                                                    float* __restrict__ out)
{
    size_t fi = ((size_t)blockIdx.x * 256 + threadIdx.x) * 4;
    int b  = (int)(fi >> 20);
    int e4 = (int)(fi & (EE - 1));
    float4 val = *(const float4*)(base + b * EE + e4);
    *(float4*)(out + fi) = val;
}

// ---------------------------------------------------------------------------
// K6c: corrections: out[b,l_sel,:] += (upd - mean_v) . Wo_h^T   (atomic)
// ---------------------------------------------------------------------------
__global__ __launch_bounds__(256) void corr_kernel(const float* __restrict__ upd,
                                                   const float* __restrict__ mean_v,
                                                   const int* __restrict__ top,
                                                   const float* __restrict__ Wo,
                                                   float* __restrict__ out)
{
    int bhu = blockIdx.x;
    int bh  = bhu / NT;
    int h   = bh & (HH - 1);
    int b   = bh >> 3;
    int tid = threadIdx.x;
    int l   = top[bhu];

    __shared__ float delta[DD];
    if (tid < DD) delta[tid] = upd[(size_t)bhu * DD + tid] - mean_v[bh * DD + tid];
    __syncthreads();

    float* orow = out + ((size_t)(b * LL + l)) * EE;
#pragma unroll
    for (int rep = 0; rep < 2; rep++) {
        int e = tid + rep * 256;
        const float* wrow = Wo + (size_t)e * EE + h * DD;
        float acc = 0.0f;
#pragma unroll
        for (int d = 0; d < DD; d++) acc += delta[d] * wrow[d];
        atomicAdd(orow + e, acc);
    }
}

// ---------------------------------------------------------------------------
extern "C" void kernel_launch(void* const* d_in, const int* in_sizes, int n_in,
                              void* d_out, int out_size, void* d_ws, size_t ws_size,
                              hipStream_t stream)
{
    const float* query = (const float*)d_in[0];
    const float* key   = (const float*)d_in[1];
    const float* value = (const float*)d_in[2];
    const int*   idxs  = (const int*)d_in[3];
    const float* Wq = (const float*)d_in[4];
    const float* bq = (const float*)d_in[5];
    const float* Wk = (const float*)d_in[6];
    const float* bk = (const float*)d_in[7];
    const float* Wv = (const float*)d_in[8];
    const float* bv = (const float*)d_in[9];
    const float* Wo = (const float*)d_in[10];
    const float* bo = (const float*)d_in[11];
    float* out = (float*)d_out;

    // workspace layout
    char* ws = (char*)d_ws;
    size_t off = 0;
    const size_t qkv_bytes = (size_t)BB * HH * LL * DD * sizeof(float); // 16 MB each
    float* q_ws = (float*)(ws + off); off += qkv_bytes;
    float* k_ws = (float*)(ws + off); off += qkv_bytes;
    float* v_ws = (float*)(ws + off); off += qkv_bytes;
    float* M_ws    = (float*)(ws + off); off += (size_t)BB * HH * LL * sizeof(float);
    int*   top_ws  = (int*)(ws + off);   off += (size_t)BB * HH * NT * sizeof(int);
    float* mean_ws = (float*)(ws + off); off += (size_t)BB * HH * DD * sizeof(float);
    float* upd_ws  = (float*)(ws + off); off += (size_t)BB * HH * NT * DD * sizeof(float);
    float* base_ws = (float*)(ws + off); off += (size_t)BB * EE * sizeof(float);

    // K1: QKV projections (split-bf16 MFMA)
    dim3 g1(EE / 128, (BB * LL) / 128, 3);
    proj_kernel<<<g1, 256, 0, stream>>>(query, key, value, Wq, Wk, Wv, bq, bk, bv,
                                        q_ws, k_ws, v_ws);
    // K2: mean of V
    meanv_kernel<<<BB * HH, 256, 0, stream>>>(v_ws, mean_ws);
    // K3: sparsity measure
    dim3 g3(BB * HH, LL / 4);
    measure_kernel<<<g3, 256, 0, stream>>>(q_ws, k_ws, idxs, M_ws);
    // K4: top-40
    topk_kernel<<<BB * HH, 256, 0, stream>>>(M_ws, top_ws);
    // K5: attention on selected rows
    attn_kernel<<<BB * HH * NT, 256, 0, stream>>>(q_ws, k_ws, v_ws, top_ws, upd_ws);
    // K6: output projection (base + broadcast + corrections)
    base_kernel<<<(BB * EE) / 4, 256, 0, stream>>>(mean_ws, Wo, bo, base_ws);
    bcast_kernel<<<(BB * LL * EE) / (256 * 4), 256, 0, stream>>>(base_ws, out);
    corr_kernel<<<BB * HH * NT, 256, 0, stream>>>(upd_ws, mean_ws, top_ws, Wo, out);
}